// Round 16
// baseline (162.218 us; speedup 1.0000x reference)
//
#include <hip/hip_runtime.h>

typedef unsigned short ushort_t;
typedef unsigned int   uint_t;
typedef signed char    i8_t;

using int32x4  = __attribute__((ext_vector_type(4))) int;
using int32x16 = __attribute__((ext_vector_type(16))) int;

#define BATCH 16
#define CIN   64
#define COUT  64
#define LSIG  16384
#define KW    128
#define LOUT  (LSIG - KW + 1)   /* 16257 */

#define NTILE 512                /* output positions per block */
#define ROWS  640                /* NTILE + 127 halo, rounded to 16 */

// ---------------- pass 1a: per-block partial max|x| (no atomics) ----------------
__global__ void k_amax_part(const float* __restrict__ x, float* __restrict__ part, int n4) {
  const float4* x4 = (const float4*)x;
  float m = 0.f;
  for (int i = blockIdx.x * blockDim.x + threadIdx.x; i < n4; i += gridDim.x * blockDim.x) {
    float4 v = x4[i];
    m = fmaxf(m, fmaxf(fmaxf(fabsf(v.x), fabsf(v.y)), fmaxf(fabsf(v.z), fabsf(v.w))));
  }
  for (int off = 32; off > 0; off >>= 1) m = fmaxf(m, __shfl_down(m, off, 64));
  __shared__ float sm[4];
  if ((threadIdx.x & 63) == 0) sm[threadIdx.x >> 6] = m;
  __syncthreads();
  if (threadIdx.x == 0)
    part[blockIdx.x] = fmaxf(fmaxf(sm[0], sm[1]), fmaxf(sm[2], sm[3]));
}

// ---------------- pass 1b: finalize -> scales[0]=amax_w, scales[1]=amax_s ----------------
__global__ void k_amax_fin(const float* __restrict__ part, float* __restrict__ scales) {
  const int t = threadIdx.x;
  float mw = (t < 64) ? part[t] : 0.f;
  float ms = 0.f;
  for (int i = t; i < 512; i += 256) ms = fmaxf(ms, part[64 + i]);
  for (int off = 32; off > 0; off >>= 1) {
    mw = fmaxf(mw, __shfl_down(mw, off, 64));
    ms = fmaxf(ms, __shfl_down(ms, off, 64));
  }
  __shared__ float sw[4], ss[4];
  if ((t & 63) == 0) { sw[t >> 6] = mw; ss[t >> 6] = ms; }
  __syncthreads();
  if (t == 0) {
    scales[0] = fmaxf(fmaxf(sw[0], sw[1]), fmaxf(sw[2], sw[3]));
    scales[1] = fmaxf(fmaxf(ss[0], ss[1]), fmaxf(ss[2], ss[3]));
  }
}

// ---------------- pass 2: quantize weights to i8, FRAGMENT order, coalesced writes ----------
// wt3[((k*4 + frag)*64 + lane)*16 + j], frag = of*2+ks, lane = hi*32+l31,
// element (o,i) = (of*32+l31, ks*32 + hi*16 + j).
__global__ void k_wprep(const float* __restrict__ w, const float* __restrict__ scales,
                        i8_t* __restrict__ wt3) {
  const float scale = scales[0] / 127.0f;
  const int k = blockIdx.x;
  const int t = threadIdx.x;
  const int frag = t >> 6, lane = t & 63;
  const int hi = lane >> 5, l31 = lane & 31;
  const int of = frag >> 1, ks = frag & 1;
  const int o = of * 32 + l31;
  const int ibase = ks * 32 + hi * 16;
  union { i8_t b[16]; uint4 u; } pk;
#pragma unroll
  for (int j = 0; j < 16; ++j) {
    const float q = rintf(w[((size_t)o * CIN + ibase + j) * KW + k] / scale); // int in [-127,127], EXACT in i8
    pk.b[j] = (i8_t)q;
  }
  *(uint4*)(wt3 + (((size_t)k * 4 + frag) * 64 + lane) * 16) = pk.u;
}

// ---------------- pass 3: signal -> i8 sigT8[b][n][i], 16B chunk c stored at slot c^((n>>1)&3) ----
__global__ void k_sprep(const float* __restrict__ sig, const float* __restrict__ scales,
                        uint4* __restrict__ sigT8) {
  __shared__ float tile[64][65];
  const float rs = 127.0f / scales[1];
  const int b = blockIdx.y;
  const int n0 = blockIdx.x * 64;
  const int t = threadIdx.x;
  {
    const int i = t >> 2, q = t & 3;
    const float4* src = (const float4*)(sig + ((size_t)(b * CIN + i)) * LSIG + n0 + q * 16);
    float4 v0 = src[0], v1 = src[1], v2 = src[2], v3 = src[3];
    float* trow = &tile[i][q * 16];
    trow[0]=v0.x; trow[1]=v0.y; trow[2]=v0.z;  trow[3]=v0.w;
    trow[4]=v1.x; trow[5]=v1.y; trow[6]=v1.z;  trow[7]=v1.w;
    trow[8]=v2.x; trow[9]=v2.y; trow[10]=v2.z; trow[11]=v2.w;
    trow[12]=v3.x; trow[13]=v3.y; trow[14]=v3.z; trow[15]=v3.w;
  }
  __syncthreads();
  // coalesced writes: consecutive t -> consecutive uint4 (block writes 4KB contiguous)
  const int nl = t >> 2, cg = t & 3;
  const int n = n0 + nl;
  const int cbase = (cg ^ ((n >> 1) & 3)) * 16;   // slot cg holds chunk cg^g(n)
  uint_t u[4];
#pragma unroll
  for (int d = 0; d < 4; ++d) {
    uint_t word = 0;
#pragma unroll
    for (int e = 0; e < 4; ++e) {
      float q = rintf(tile[cbase + d * 4 + e][nl] * rs);
      q = fminf(127.0f, fmaxf(-127.0f, q));
      word |= ((uint_t)(unsigned char)(i8_t)(int)q) << (8 * e);
    }
    u[d] = word;
  }
  sigT8[((size_t)b * LSIG + n) * 4 + cg] = make_uint4(u[0], u[1], u[2], u[3]);
}

// ---------------- pass 4: the conv (implicit GEMM, i8 32x32x32 MFMA) ----------------
// block: 256 threads = 4 waves; each wave owns 128 output positions x all 64 Cout.
// grid = 32 x 16 = 512 blocks = 2 blocks/CU, 8 waves/CU. LDS tile 40KB.
// R16: MINIMAL-VALU ADDRESSING. 8-tap unrolled loop; the swizzle term ((r>>1)&3) is
// invariant under tap += 8, so all 16 LDS base offsets boffv[u][ks] are precomputed
// once (VGPRs, statically indexed); per-tap addressing = 1-2 v_add + offset:
// immediates (nf*2048 in ds imm, f*1024 in global imm). No sched_barriers — the
// B ping-pong register dependency already limits prefetch to depth 1; setprio wraps
// the 16-MFMA cluster. A single-buffered, reloaded after its last use each tap.
#define TAP(U, BC, BN) do {                                                            \
    { const uint_t vb_ = vbase + ((U) == 7 ? 512u : 0u);                               \
      const int un_ = ((U) + 1) & 7;                                                   \
      _Pragma("unroll") for (int ks = 0; ks < 2; ++ks) {                               \
        const i8_t* p_ = lds8 + vb_ + boffv[un_ * 2 + ks];                             \
        _Pragma("unroll") for (int nf = 0; nf < 4; ++nf)                               \
          BN[ks][nf] = *(const int32x4*)(p_ + nf * 2048);                              \
      } }                                                                              \
    __builtin_amdgcn_s_setprio(1);                                                     \
    _Pragma("unroll") for (int ks = 0; ks < 2; ++ks)                                   \
      _Pragma("unroll") for (int of = 0; of < 2; ++of)                                 \
        _Pragma("unroll") for (int nf = 0; nf < 4; ++nf)                               \
          acc[of][nf] = __builtin_amdgcn_mfma_i32_32x32x32_i8(A[of * 2 + ks], BC[ks][nf], acc[of][nf], 0, 0, 0); \
    __builtin_amdgcn_s_setprio(0);                                                     \
    { const i8_t* pa_ = wa3 + (aoff + ((U) + 1) * 4096);                               \
      _Pragma("unroll") for (int f = 0; f < 4; ++f)                                    \
        A[f] = *(const int32x4*)(pa_ + f * 1024); }                                    \
  } while (0)

__global__ __launch_bounds__(256, 2) void k_conv(
    const uint4* __restrict__ sigT8, const i8_t* __restrict__ wt3,
    const float* __restrict__ scales, const float* __restrict__ bias,
    float* __restrict__ out)
{
  __shared__ __align__(16) i8_t lds8[ROWS * 64];   // 40 KB
  const int b  = blockIdx.y;
  const int n0 = blockIdx.x * NTILE;
  const int t  = threadIdx.x;
  const int wv = t >> 6;
  const int lane = t & 63;
  const int l31 = lane & 31, hi = lane >> 5;

  // stage 640 rows x 64B = one contiguous 40KB span of sigT8 (clamped at buffer end;
  // overrun rows only feed store-masked outputs)
  {
    const size_t base = ((size_t)b * LSIG + n0) * 4;       // 4 uint4 per 64B row
    const size_t lim  = (size_t)BATCH * LSIG * 4;
    uint4* dst = (uint4*)lds8;
    for (int c = t; c < ROWS * 4; c += 256) {
      size_t g = base + c;
      if (g >= lim) g = lim - 1;
      dst[c] = sigT8[g];
    }
  }
  __syncthreads();

  int32x16 acc[2][4];
#pragma unroll
  for (int i = 0; i < 2; ++i)
#pragma unroll
    for (int j = 0; j < 4; ++j)
#pragma unroll
      for (int r = 0; r < 16; ++r) acc[i][j][r] = 0;

  const i8_t* wa3 = wt3 + (size_t)lane * 16;   // fragment-ordered; +tap*4096 +frag*1024
  const int rowbase = wv * 128 + l31;

  // precomputed LDS byte offsets (per-lane, static over the 8-tap-strided loop):
  // boffv[u*2+ks] = (rowbase+u)*64 + ((ks*2+hi) ^ (((l31+u)>>1)&3))*16
  uint_t boffv[16];
#pragma unroll
  for (int u = 0; u < 8; ++u)
#pragma unroll
    for (int ks = 0; ks < 2; ++ks)
      boffv[u * 2 + ks] = (uint_t)((rowbase + u) * 64 +
                          (((ks * 2 + hi) ^ (((l31 + u) >> 1) & 3)) << 4));

  int32x4 A[4], Bb0[2][4], Bb1[2][4];
  // prologue: A for tap 0; B for tap 0 into Bb0
#pragma unroll
  for (int f = 0; f < 4; ++f) A[f] = *(const int32x4*)(wa3 + f * 1024);
#pragma unroll
  for (int ks = 0; ks < 2; ++ks) {
    const i8_t* p_ = lds8 + boffv[ks];
#pragma unroll
    for (int nf = 0; nf < 4; ++nf)
      Bb0[ks][nf] = *(const int32x4*)(p_ + nf * 2048);
  }

  uint_t vbase = 0, aoff = 0;
  for (int tp8 = 0; tp8 < KW; tp8 += 8) {
    TAP(0, Bb0, Bb1);
    TAP(1, Bb1, Bb0);
    TAP(2, Bb0, Bb1);
    TAP(3, Bb1, Bb0);
    TAP(4, Bb0, Bb1);
    TAP(5, Bb1, Bb0);
    TAP(6, Bb0, Bb1);
    TAP(7, Bb1, Bb0);
    vbase += 512;
    aoff  += 32768;
  }
  // final iteration's tap-7 prefetch targets tap 128: B rows <= 639 (inside the
  // 640-row tile) and A reads land in wt3's slack region; values never used.

  const float sc = (scales[0] / 127.0f) * (scales[1] / 127.0f);
#pragma unroll
  for (int of = 0; of < 2; ++of) {
#pragma unroll
    for (int nf = 0; nf < 4; ++nf) {
      const int n = n0 + wv * 128 + nf * 32 + l31;
      if (n < LOUT) {
#pragma unroll
        for (int r = 0; r < 16; ++r) {
          // D: col = lane&31 (= n), row o = of*32 + 4*hi + (r&3) + 8*(r>>2)  [m74/m101 layout]
          const int o = of * 32 + 4 * hi + (r & 3) + 8 * (r >> 2);
          out[((size_t)b * COUT + o) * LOUT + n] = (float)acc[of][nf][r] * sc + bias[o];
        }
      }
    }
  }
}

extern "C" void kernel_launch(void* const* d_in, const int* in_sizes, int n_in,
                              void* d_out, int out_size, void* d_ws, size_t ws_size,
                              hipStream_t stream) {
  const float* sig  = (const float*)d_in[0];
  const float* w    = (const float*)d_in[1];
  const float* bias = (const float*)d_in[2];
  float* out = (float*)d_out;

  // workspace: [0,8): scales (2 f32) | [64, 64+2304): partials (w:64, s:512)
  //            | [4096, 4096+512KB+4KB slack): wt3 | [2MB, 2MB+16MB): sigT8
  float* scales = (float*)d_ws;
  float* part   = (float*)((char*)d_ws + 64);
  i8_t*  wt3    = (i8_t*)((char*)d_ws + 4096);
  uint4* sigT8  = (uint4*)((char*)d_ws + (size_t)(2u << 20));

  hipLaunchKernelGGL(k_amax_part, dim3(64),  dim3(256), 0, stream, w,   part,      COUT * CIN * KW / 4);
  hipLaunchKernelGGL(k_amax_part, dim3(512), dim3(256), 0, stream, sig, part + 64, BATCH * CIN * LSIG / 4);
  hipLaunchKernelGGL(k_amax_fin,  dim3(1),   dim3(256), 0, stream, (const float*)part, scales);
  hipLaunchKernelGGL(k_wprep, dim3(KW), dim3(256), 0, stream, w, (const float*)scales, wt3);
  hipLaunchKernelGGL(k_sprep, dim3(LSIG / 64, BATCH), dim3(256), 0, stream, sig, (const float*)scales, sigT8);
  hipLaunchKernelGGL(k_conv, dim3((LOUT + NTILE - 1) / NTILE, BATCH), dim3(256), 0, stream,
                     sigT8, wt3, (const float*)scales, bias, out);
}

// Round 17
// 158.999 us; speedup vs baseline: 1.0202x; 1.0202x over previous
//
#include <hip/hip_runtime.h>

typedef unsigned short ushort_t;
typedef unsigned int   uint_t;
typedef signed char    i8_t;

using int32x4  = __attribute__((ext_vector_type(4))) int;
using int32x16 = __attribute__((ext_vector_type(16))) int;

#define BATCH 16
#define CIN   64
#define COUT  64
#define LSIG  16384
#define KW    128
#define LOUT  (LSIG - KW + 1)   /* 16257 */

#define NTILE 512                /* output positions per block */
#define ROWS  640                /* NTILE + 127 halo, rounded to 16 */

// ---------------- pass 1a: per-block partial max|x| (no atomics) ----------------
__global__ void k_amax_part(const float* __restrict__ x, float* __restrict__ part, int n4) {
  const float4* x4 = (const float4*)x;
  float m = 0.f;
  for (int i = blockIdx.x * blockDim.x + threadIdx.x; i < n4; i += gridDim.x * blockDim.x) {
    float4 v = x4[i];
    m = fmaxf(m, fmaxf(fmaxf(fabsf(v.x), fabsf(v.y)), fmaxf(fabsf(v.z), fabsf(v.w))));
  }
  for (int off = 32; off > 0; off >>= 1) m = fmaxf(m, __shfl_down(m, off, 64));
  __shared__ float sm[4];
  if ((threadIdx.x & 63) == 0) sm[threadIdx.x >> 6] = m;
  __syncthreads();
  if (threadIdx.x == 0)
    part[blockIdx.x] = fmaxf(fmaxf(sm[0], sm[1]), fmaxf(sm[2], sm[3]));
}

// ---------------- pass 1b: finalize -> scales[0]=amax_w, scales[1]=amax_s ----------------
__global__ void k_amax_fin(const float* __restrict__ part, float* __restrict__ scales) {
  const int t = threadIdx.x;
  float mw = (t < 64) ? part[t] : 0.f;
  float ms = 0.f;
  for (int i = t; i < 512; i += 256) ms = fmaxf(ms, part[64 + i]);
  for (int off = 32; off > 0; off >>= 1) {
    mw = fmaxf(mw, __shfl_down(mw, off, 64));
    ms = fmaxf(ms, __shfl_down(ms, off, 64));
  }
  __shared__ float sw[4], ss[4];
  if ((t & 63) == 0) { sw[t >> 6] = mw; ss[t >> 6] = ms; }
  __syncthreads();
  if (t == 0) {
    scales[0] = fmaxf(fmaxf(sw[0], sw[1]), fmaxf(sw[2], sw[3]));
    scales[1] = fmaxf(fmaxf(ss[0], ss[1]), fmaxf(ss[2], ss[3]));
  }
}

// ---------------- pass 2: quantize weights to i8, FRAGMENT order, coalesced writes ----------
// wt3[((k*4 + frag)*64 + lane)*16 + j], frag = of*2+ks, lane = hi*32+l31,
// element (o,i) = (of*32+l31, ks*32 + hi*16 + j).
__global__ void k_wprep(const float* __restrict__ w, const float* __restrict__ scales,
                        i8_t* __restrict__ wt3) {
  const float scale = scales[0] / 127.0f;
  const int k = blockIdx.x;
  const int t = threadIdx.x;
  const int frag = t >> 6, lane = t & 63;
  const int hi = lane >> 5, l31 = lane & 31;
  const int of = frag >> 1, ks = frag & 1;
  const int o = of * 32 + l31;
  const int ibase = ks * 32 + hi * 16;
  union { i8_t b[16]; uint4 u; } pk;
#pragma unroll
  for (int j = 0; j < 16; ++j) {
    const float q = rintf(w[((size_t)o * CIN + ibase + j) * KW + k] / scale); // int in [-127,127], EXACT in i8
    pk.b[j] = (i8_t)q;
  }
  *(uint4*)(wt3 + (((size_t)k * 4 + frag) * 64 + lane) * 16) = pk.u;
}

// ---------------- pass 3: signal -> i8 sigT8[b][n][i], 16B chunk c stored at slot c^((n>>1)&3) ----
__global__ void k_sprep(const float* __restrict__ sig, const float* __restrict__ scales,
                        uint4* __restrict__ sigT8) {
  __shared__ float tile[64][65];
  const float rs = 127.0f / scales[1];
  const int b = blockIdx.y;
  const int n0 = blockIdx.x * 64;
  const int t = threadIdx.x;
  {
    const int i = t >> 2, q = t & 3;
    const float4* src = (const float4*)(sig + ((size_t)(b * CIN + i)) * LSIG + n0 + q * 16);
    float4 v0 = src[0], v1 = src[1], v2 = src[2], v3 = src[3];
    float* trow = &tile[i][q * 16];
    trow[0]=v0.x; trow[1]=v0.y; trow[2]=v0.z;  trow[3]=v0.w;
    trow[4]=v1.x; trow[5]=v1.y; trow[6]=v1.z;  trow[7]=v1.w;
    trow[8]=v2.x; trow[9]=v2.y; trow[10]=v2.z; trow[11]=v2.w;
    trow[12]=v3.x; trow[13]=v3.y; trow[14]=v3.z; trow[15]=v3.w;
  }
  __syncthreads();
  // coalesced writes: consecutive t -> consecutive uint4 (block writes 4KB contiguous)
  const int nl = t >> 2, cg = t & 3;
  const int n = n0 + nl;
  const int cbase = (cg ^ ((n >> 1) & 3)) * 16;   // slot cg holds chunk cg^g(n)
  uint_t u[4];
#pragma unroll
  for (int d = 0; d < 4; ++d) {
    uint_t word = 0;
#pragma unroll
    for (int e = 0; e < 4; ++e) {
      float q = rintf(tile[cbase + d * 4 + e][nl] * rs);
      q = fminf(127.0f, fmaxf(-127.0f, q));
      word |= ((uint_t)(unsigned char)(i8_t)(int)q) << (8 * e);
    }
    u[d] = word;
  }
  sigT8[((size_t)b * LSIG + n) * 4 + cg] = make_uint4(u[0], u[1], u[2], u[3]);
}

// ---------------- pass 4: the conv (implicit GEMM, i8 32x32x32 MFMA) ----------------
// block: 256 threads = 4 waves; each wave owns 128 output positions x all 64 Cout.
// grid = 32 x 16 = 512 blocks = 2 blocks/CU, 8 waves/CU. LDS tile 40KB.
// R17 = R15's schedule + BLOCK-PARITY ANTI-PHASE SKEW. The two waves sharing a SIMD
// are block0.wv_k and block1.wv_k (2 blocks/CU, round-robin wave placement). R11's
// skew keyed on wv gave SIMD-sharing pairs identical sleeps — invalid test. Here the
// odd-parity co-resident block sleeps ~half a tap-period (1152 cyc) once after
// staging, so each SIMD's two waves run in anti-phase: one wave's ~1170-cyc MFMA
// cluster covers its partner's LDS burst, turning the MFMA+LDS SUM into a MAX.
#define NF_GROUP(T, KS, NF, BCUR, BNXT) do {                                           \
    { const int r_ = rowbase + (T) + 1 + (NF) * 32;                                    \
      const int slot_ = (((KS) * 2 + hi) ^ ((r_ >> 1) & 3));                           \
      BNXT[KS][NF] = *(const int32x4*)(lds8 + r_ * 64 + slot_ * 16); }                 \
    __builtin_amdgcn_sched_barrier(0);                                                 \
    __builtin_amdgcn_s_setprio(1);                                                     \
    acc[0][NF] = __builtin_amdgcn_mfma_i32_32x32x32_i8(A[(KS)],     BCUR[KS][NF], acc[0][NF], 0, 0, 0); \
    acc[1][NF] = __builtin_amdgcn_mfma_i32_32x32x32_i8(A[2 + (KS)], BCUR[KS][NF], acc[1][NF], 0, 0, 0); \
    __builtin_amdgcn_s_setprio(0);                                                     \
    __builtin_amdgcn_sched_barrier(0);                                                 \
  } while (0)

#define KS_I8(T, KS, BCUR, BNXT) do {                                                  \
    NF_GROUP(T, KS, 0, BCUR, BNXT);                                                    \
    NF_GROUP(T, KS, 1, BCUR, BNXT);                                                    \
    NF_GROUP(T, KS, 2, BCUR, BNXT);                                                    \
    NF_GROUP(T, KS, 3, BCUR, BNXT);                                                    \
    { const char* pa_ = wa3 + (size_t)((T) + 1) * 4096;                                \
      A[(KS)]     = *(const int32x4*)(pa_ + (KS) * 1024);                              \
      A[2 + (KS)] = *(const int32x4*)(pa_ + (2 + (KS)) * 1024); }                      \
    __builtin_amdgcn_sched_barrier(0);                                                 \
  } while (0)

__global__ __launch_bounds__(256, 2) void k_conv(
    const uint4* __restrict__ sigT8, const i8_t* __restrict__ wt3,
    const float* __restrict__ scales, const float* __restrict__ bias,
    float* __restrict__ out)
{
  __shared__ __align__(16) i8_t lds8[ROWS * 64];   // 40 KB
  const int b  = blockIdx.y;
  const int n0 = blockIdx.x * NTILE;
  const int t  = threadIdx.x;
  const int wv = t >> 6;
  const int lane = t & 63;
  const int l31 = lane & 31, hi = lane >> 5;

  // stage 640 rows x 64B = one contiguous 40KB span of sigT8 (clamped at buffer end;
  // overrun rows only feed store-masked outputs)
  {
    const size_t base = ((size_t)b * LSIG + n0) * 4;       // 4 uint4 per 64B row
    const size_t lim  = (size_t)BATCH * LSIG * 4;
    uint4* dst = (uint4*)lds8;
    for (int c = t; c < ROWS * 4; c += 256) {
      size_t g = base + c;
      if (g >= lim) g = lim - 1;
      dst[c] = sigT8[g];
    }
  }
  __syncthreads();

  // ---- anti-phase skew: odd co-resident block sleeps ~half a tap-period ----
  if ((blockIdx.x ^ blockIdx.y) & 1) __builtin_amdgcn_s_sleep(18);   // 18*64 = 1152 cyc

  int32x16 acc[2][4];
#pragma unroll
  for (int i = 0; i < 2; ++i)
#pragma unroll
    for (int j = 0; j < 4; ++j)
#pragma unroll
      for (int r = 0; r < 16; ++r) acc[i][j][r] = 0;

  // A: fragment-ordered; per-lane addr = tap*4096 + frag*1024 + lane*16 (bytes)
  // A[of*2+ks]; NF_GROUP uses A[KS] (of=0) and A[2+KS] (of=1)
  const char* wa3 = (const char*)wt3 + (size_t)lane * 16;
  const int rowbase = wv * 128 + l31;

  int32x4 A[4], BbE[2][4], BbO[2][4];
  // prologue: full A for tap 0; B cur-set for tap 0 (ks 0,1)
#pragma unroll
  for (int of = 0; of < 2; ++of)
#pragma unroll
    for (int ks = 0; ks < 2; ++ks)
      A[of * 2 + ks] = *(const int32x4*)(wa3 + (size_t)(of * 2 + ks) * 1024);
#pragma unroll
  for (int ks = 0; ks < 2; ++ks)
#pragma unroll
    for (int nf = 0; nf < 4; ++nf) {
      const int r_ = rowbase + nf * 32;
      const int slot_ = ((ks * 2 + hi) ^ ((r_ >> 1) & 3));
      BbE[ks][nf] = *(const int32x4*)(lds8 + r_ * 64 + slot_ * 16);
    }

  for (int tp = 0; tp < KW; tp += 2) {
    KS_I8(tp,     0, BbE, BbO);
    KS_I8(tp,     1, BbE, BbO);
    KS_I8(tp + 1, 0, BbO, BbE);
    KS_I8(tp + 1, 1, BbO, BbE);
  }
  // at tp=127 prefetches target tap 128: B rows <= 639 (inside 640-row tile), A reads
  // land in wt3's slack region; both values are never used.

  const float sc = (scales[0] / 127.0f) * (scales[1] / 127.0f);
#pragma unroll
  for (int of = 0; of < 2; ++of) {
#pragma unroll
    for (int nf = 0; nf < 4; ++nf) {
      const int n = n0 + wv * 128 + nf * 32 + l31;
      if (n < LOUT) {
#pragma unroll
        for (int r = 0; r < 16; ++r) {
          // D: col = lane&31 (= n), row o = of*32 + 4*hi + (r&3) + 8*(r>>2)  [m74/m101 layout]
          const int o = of * 32 + 4 * hi + (r & 3) + 8 * (r >> 2);
          out[((size_t)b * COUT + o) * LOUT + n] = (float)acc[of][nf][r] * sc + bias[o];
        }
      }
    }
  }
}

extern "C" void kernel_launch(void* const* d_in, const int* in_sizes, int n_in,
                              void* d_out, int out_size, void* d_ws, size_t ws_size,
                              hipStream_t stream) {
  const float* sig  = (const float*)d_in[0];
  const float* w    = (const float*)d_in[1];
  const float* bias = (const float*)d_in[2];
  float* out = (float*)d_out;

  // workspace: [0,8): scales (2 f32) | [64, 64+2304): partials (w:64, s:512)
  //            | [4096, 4096+512KB+4KB slack): wt3 | [2MB, 2MB+16MB): sigT8
  float* scales = (float*)d_ws;
  float* part   = (float*)((char*)d_ws + 64);
  i8_t*  wt3    = (i8_t*)((char*)d_ws + 4096);
  uint4* sigT8  = (uint4*)((char*)d_ws + (size_t)(2u << 20));

  hipLaunchKernelGGL(k_amax_part, dim3(64),  dim3(256), 0, stream, w,   part,      COUT * CIN * KW / 4);
  hipLaunchKernelGGL(k_amax_part, dim3(512), dim3(256), 0, stream, sig, part + 64, BATCH * CIN * LSIG / 4);
  hipLaunchKernelGGL(k_amax_fin,  dim3(1),   dim3(256), 0, stream, (const float*)part, scales);
  hipLaunchKernelGGL(k_wprep, dim3(KW), dim3(256), 0, stream, w, (const float*)scales, wt3);
  hipLaunchKernelGGL(k_sprep, dim3(LSIG / 64, BATCH), dim3(256), 0, stream, sig, (const float*)scales, sigT8);
  hipLaunchKernelGGL(k_conv, dim3((LOUT + NTILE - 1) / NTILE, BATCH), dim3(256), 0, stream,
                     sigT8, wt3, (const float*)scales, bias, out);
}